// Round 13
// baseline (77.697 us; speedup 1.0000x reference)
//
#include <hip/hip_runtime.h>
#include <hip/hip_bf16.h>

#define BSZ 512
#define DIM 768
#define NTYPES 16
#define MARGIN 1.0f
#define PITCH (DIM + 8)       // 776 ushorts = 1552 B rows (16B-aligned)

typedef short bf16x8 __attribute__((ext_vector_type(8)));
typedef float f32x4 __attribute__((ext_vector_type(4)));

// ---------------------------------------------------------------------------
// Kernel 1: full-K distance tiles via bf16 MFMA — no K-split, no partials.
// grid = 256 = 16x16 tiles of 32x32 (1 block/CU).  Staging (fixed vs R12):
// wave w stages rows [16w, 16w+16); per row 3 wave-wide float4 loads
// (c4 = p*64 + lane) = 1KB contiguous per instruction, fully coalesced
// (R12's row-per-thread mapping put adjacent lanes 768B apart -> 4x L2
// transactions -> +2.5us).  fp32 row norm: per-lane accumulate + 6-step
// butterfly shfl_xor.  LDS writes 8B/lane stride-8 = 2-way (free).
// MFMA phase: each of 4 waves computes one 16x16 tile: 24 K-chunks x
// (2 ds_read_b128 + 1 mfma_f32_16x16x32_bf16).  Epilogue writes FINAL
// d = sqrt(max(na+nb-2dot,0)); diagonal forced to exact 0 (reference's
// sq>0 guard).  Frag layouts (m89/m120-verified): A/B lane m=lane&15 reads
// 8 consecutive k at k0=8*(lane>>4); C/D col=lane&15, row=4*(lane>>4)+reg.
// Block 0 zeroes out[0] (cross-boundary visibility proven R6-R12).
// NO grid sync / NO acquire-release (R5/R7/R9: buffer_inv storms).
// ---------------------------------------------------------------------------
__global__ __launch_bounds__(256) void dist_kernel(
    const float* __restrict__ emb,
    float* __restrict__ dist,       // [BSZ][BSZ]
    float* __restrict__ out)
{
    const int tid = threadIdx.x;
    const int blk = blockIdx.x;
    const int ti = blk >> 4, tj = blk & 15;
    const int i0 = ti * 32, j0 = tj * 32;

    if (blk == 0 && tid == 0) out[0] = 0.f;   // out is poisoned each launch

    __shared__ ushort sE[64][PITCH];   // rows 0..31 = A, 32..63 = B
    __shared__ float nrm64[64];

    const int lane = tid & 63;
    const int w = tid >> 6;

    // ---- stage + fp32 norms: wave w -> rows [16w, 16w+16) ----
    for (int rr = 0; rr < 16; ++rr) {
        const int row = w * 16 + rr;
        const int grow = (row < 32) ? (i0 + row) : (j0 + row - 32);
        const float* gsrc = emb + (size_t)grow * DIM;
        float np = 0.f;
        #pragma unroll
        for (int p = 0; p < 3; ++p) {
            const int c4 = p * 64 + lane;          // coalesced: 1KB/wave-load
            const float4 v = *(const float4*)(gsrc + c4 * 4);
            np = fmaf(v.x, v.x, np); np = fmaf(v.y, v.y, np);
            np = fmaf(v.z, v.z, np); np = fmaf(v.w, v.w, np);
            __hip_bfloat162 h0 = __float22bfloat162_rn(make_float2(v.x, v.y));
            __hip_bfloat162 h1 = __float22bfloat162_rn(make_float2(v.z, v.w));
            unsigned u0, u1;
            __builtin_memcpy(&u0, &h0, 4);
            __builtin_memcpy(&u1, &h1, 4);
            *(uint2*)&sE[row][c4 * 4] = make_uint2(u0, u1);
        }
        #pragma unroll
        for (int off = 1; off < 64; off <<= 1) np += __shfl_xor(np, off);
        if (lane == 0) nrm64[row] = np;
    }
    __syncthreads();

    // ---- MFMA: wave w -> 16x16 tile (wr=w>>1 row-half, wc=w&1 col-half)
    const int wr = w >> 1, wc = w & 1;
    const int m = lane & 15;
    const int q = lane >> 4;          // 0..3

    const ushort* arow = &sE[wr * 16 + m][q * 8];
    const ushort* brow = &sE[32 + wc * 16 + m][q * 8];

    f32x4 acc = {0.f, 0.f, 0.f, 0.f};
    #pragma unroll
    for (int kc = 0; kc < DIM / 32; ++kc) {        // 24 chunks
        const bf16x8 af = *(const bf16x8*)(arow + kc * 32);
        const bf16x8 bf = *(const bf16x8*)(brow + kc * 32);
        acc = __builtin_amdgcn_mfma_f32_16x16x32_bf16(af, bf, acc, 0, 0, 0);
    }

    // ---- epilogue: C/D col=m, row=4q+r; d = sqrt(max(na+nb-2dot,0))
    const float nb = nrm64[32 + wc * 16 + m];
    const int gcol = j0 + wc * 16 + m;
    #pragma unroll
    for (int r = 0; r < 4; ++r) {
        const int lrow = wr * 16 + 4 * q + r;
        const int grow = i0 + lrow;
        const float na = nrm64[lrow];
        float d = sqrtf(fmaxf(na + nb - 2.f * acc[r], 0.f));
        if (grow == gcol) d = 0.f;     // exact diagonal (reference sq>0 guard)
        dist[(size_t)grow * BSZ + gcol] = d;
    }
}

// ---------------------------------------------------------------------------
// Kernel 2: per-anchor triplet sum, self-contained finalize (unchanged from
// R12).  j-loop is one coalesced dist load; ballot compaction -> |P|x|N|
// scan.  Each block computes V redundantly from a local LDS type-histogram
// and adds (blocksum/V) to out[0] with ONE plain device atomicAdd — no
// acquire/release, no ticket.  Block 0 adds the closed-form invalid-triplet
// term (B^3-V)*margin/V (reference adds margin to ALL entries pre-clamp,
// so each invalid triplet contributes exactly margin).
// ---------------------------------------------------------------------------
__global__ __launch_bounds__(256) void triplet_kernel(
    const float* __restrict__ dist, const int* __restrict__ types,
    float* __restrict__ out)
{
    const int a = blockIdx.x;
    const int tid = threadIdx.x;
    const int lane = tid & 63;
    __shared__ float pos[BSZ], neg[BSZ];
    __shared__ int npos, nneg;
    __shared__ float wsum[4];
    __shared__ int cnt[NTYPES];
    if (tid == 0) { npos = 0; nneg = 0; }
    if (tid < NTYPES) cnt[tid] = 0;
    const int ta = types[a];
    __syncthreads();

    const size_t rb = (size_t)a * BSZ;

    for (int j = tid; j < BSZ; j += 256) {
        const int tj = types[j];
        atomicAdd(&cnt[tj], 1);                      // local histogram for V
        const float d = dist[rb + j];
        const bool isp = (tj == ta);
        const unsigned long long mm = __ballot(isp);
        const unsigned long long below = mm & ((1ull << lane) - 1ull);
        const int cp = __popcll(mm);
        int basep = 0, basen = 0;
        if (lane == 0) {
            basep = atomicAdd(&npos, cp);
            basen = atomicAdd(&nneg, 64 - cp);
        }
        basep = __shfl(basep, 0);
        basen = __shfl(basen, 0);
        const int pbelow = (int)__popcll(below);
        if (isp) pos[basep + pbelow] = d;
        else     neg[basen + (lane - pbelow)] = d;
    }
    __syncthreads();
    const int np = npos, nn = nneg;

    float local = 0.f;
    for (int pi = 0; pi < np; ++pi) {
        const float dpm = pos[pi] + MARGIN;          // broadcast LDS read
        for (int n = tid; n < nn; n += 256)
            local += fmaxf(dpm - neg[n], 0.f);
    }

    #pragma unroll
    for (int off = 32; off > 0; off >>= 1) local += __shfl_down(local, off);
    if (lane == 0) wsum[tid >> 6] = local;
    __syncthreads();
    if (tid == 0) {
        long long V = 0;
        #pragma unroll
        for (int t = 0; t < NTYPES; ++t) {
            long long c = cnt[t];
            V += c * c * (long long)(BSZ - c);
        }
        double blocksum = (double)wsum[0] + (double)wsum[1]
                        + (double)wsum[2] + (double)wsum[3];
        float contrib = (float)(blocksum / (double)V);
        if (a == 0) {
            const long long B3 = (long long)BSZ * BSZ * BSZ;
            contrib += (float)((double)(B3 - V) * (double)MARGIN / (double)V);
        }
        atomicAdd(out, contrib);                     // plain relaxed atomic
    }
}

extern "C" void kernel_launch(void* const* d_in, const int* in_sizes, int n_in,
                              void* d_out, int out_size, void* d_ws, size_t ws_size,
                              hipStream_t stream) {
    const int* types = (const int*)d_in[0];
    const float* emb = (const float*)d_in[1];
    float* out = (float*)d_out;

    float* dist = (float*)d_ws;      // 1 MB

    dist_kernel<<<256, 256, 0, stream>>>(emb, dist, out);
    triplet_kernel<<<BSZ, 256, 0, stream>>>(dist, types, out);
}

// Round 14
// 73.554 us; speedup vs baseline: 1.0563x; 1.0563x over previous
//
#include <hip/hip_runtime.h>
#include <hip/hip_bf16.h>

#define BSZ 512
#define DIM 768
#define KSPLIT 4
#define KSEG (DIM / KSPLIT)   // 192
#define TILE 64
#define NTYPES 16
#define MARGIN 1.0f
#define LDSPITCH (KSEG + 8)   // 200 ushorts = 400 B rows (16B-aligned, 2-way max)

typedef short bf16x8 __attribute__((ext_vector_type(8)));
typedef float f32x4 __attribute__((ext_vector_type(4)));

// ---------------------------------------------------------------------------
// Kernel 1: K-split partial dot GEMM via bf16 MFMA (16x16x32).
// MEASURED BEST (R11: 73.8us total).  grid = 256 = 4 ksplits x 64 tiles
// (1 block/CU).  64x64 tile per block: stage A(64)+B(64) rows x KSEG=192
// as bf16 into row-major LDS (51 KB; one barrier; fp32->bf16 packed cvt in
// the staging path — 25 MB total grid read vs 50 MB for full-K 32x32 tiles,
// which regressed in R12/R13), then each of 4 waves computes a 16x64 strip:
// per K-chunk of 32, 1 A-frag + 4 B-frag ds_read_b128 feed 4 independent
// MFMA chains (depth 6 each — good ILP).  Frag layouts (m89/m120-verified):
// A/B lane m=lane&15 reads 8 consecutive k at k0=8*(lane>>4); C/D
// col=lane&15, row=4*(lane>>4)+reg.  Diagonal of summed product = squared
// norms -> ndiag (d(a,a)==0 exactly).  Block 0 zeroes out[0]
// (cross-boundary visibility proven R6-R13).  NO grid sync / NO
// acquire-release (R5/R7/R9: buffer_inv cache-maintenance storms cost
// 7-50us).  bf16 quantization: |delta d| ~2e-3 << 0.34 threshold; measured
// absmax 0.0 (errors cancel in the 7.9M-term average).
// ---------------------------------------------------------------------------
__global__ __launch_bounds__(256) void dot_partial_kernel(
    const float* __restrict__ emb,
    float* __restrict__ part,       // [KSPLIT][BSZ][BSZ]
    float* __restrict__ ndiag,      // [KSPLIT][BSZ]
    float* __restrict__ out)
{
    const int tid = threadIdx.x;
    const int blk = blockIdx.x;
    const int ks = blk >> 6;          // 0..3
    const int tile = blk & 63;        // 0..63
    const int ti = tile >> 3, tj = tile & 7;
    const int i0 = ti * TILE, j0 = tj * TILE;

    if (blk == 0 && tid == 0) out[0] = 0.f;   // out is poisoned each launch

    __shared__ ushort sA[TILE][LDSPITCH];
    __shared__ ushort sB[TILE][LDSPITCH];

    // ---- stage 128 rows x 192 floats -> bf16 LDS (coalesced: 48 float4/row)
    #pragma unroll
    for (int it = 0; it < 24; ++it) {
        const int flat = it * 256 + tid;      // 0..6143
        const int row = flat / 48;            // 0..127
        const int c4 = flat - row * 48;       // 0..47
        const int grow = (row < TILE) ? (i0 + row) : (j0 + row - TILE);
        const float4 v = *(const float4*)(emb + (size_t)grow * DIM + ks * KSEG + c4 * 4);
        __hip_bfloat162 h0 = __float22bfloat162_rn(make_float2(v.x, v.y));
        __hip_bfloat162 h1 = __float22bfloat162_rn(make_float2(v.z, v.w));
        unsigned u0, u1;
        __builtin_memcpy(&u0, &h0, 4);
        __builtin_memcpy(&u1, &h1, 4);
        ushort* dst = (row < TILE) ? &sA[row][c4 * 4] : &sB[row - TILE][c4 * 4];
        *(uint2*)dst = make_uint2(u0, u1);
    }
    __syncthreads();

    // ---- MFMA: wave w -> rows [w*16, w*16+16), all 64 cols
    const int lane = tid & 63;
    const int w = tid >> 6;
    const int m = lane & 15;
    const int q = lane >> 4;          // 0..3

    f32x4 acc0 = {0.f, 0.f, 0.f, 0.f};
    f32x4 acc1 = {0.f, 0.f, 0.f, 0.f};
    f32x4 acc2 = {0.f, 0.f, 0.f, 0.f};
    f32x4 acc3 = {0.f, 0.f, 0.f, 0.f};

    const ushort* arow = &sA[w * 16 + m][q * 8];
    const ushort* b0r = &sB[0 * 16 + m][q * 8];
    const ushort* b1r = &sB[1 * 16 + m][q * 8];
    const ushort* b2r = &sB[2 * 16 + m][q * 8];
    const ushort* b3r = &sB[3 * 16 + m][q * 8];

    #pragma unroll
    for (int kc = 0; kc < KSEG / 32; ++kc) {       // 6 chunks
        const bf16x8 af = *(const bf16x8*)(arow + kc * 32);
        const bf16x8 bf0 = *(const bf16x8*)(b0r + kc * 32);
        const bf16x8 bf1 = *(const bf16x8*)(b1r + kc * 32);
        const bf16x8 bf2 = *(const bf16x8*)(b2r + kc * 32);
        const bf16x8 bf3 = *(const bf16x8*)(b3r + kc * 32);
        acc0 = __builtin_amdgcn_mfma_f32_16x16x32_bf16(af, bf0, acc0, 0, 0, 0);
        acc1 = __builtin_amdgcn_mfma_f32_16x16x32_bf16(af, bf1, acc1, 0, 0, 0);
        acc2 = __builtin_amdgcn_mfma_f32_16x16x32_bf16(af, bf2, acc2, 0, 0, 0);
        acc3 = __builtin_amdgcn_mfma_f32_16x16x32_bf16(af, bf3, acc3, 0, 0, 0);
    }

    // ---- epilogue: C/D layout col=m, row=4q+r
    float* pbuf = part + (size_t)ks * BSZ * BSZ;
    const int gi = i0 + w * 16 + 4 * q;
    #pragma unroll
    for (int r = 0; r < 4; ++r) {
        float* prow = pbuf + (size_t)(gi + r) * BSZ + j0;
        prow[0 * 16 + m] = acc0[r];
        prow[1 * 16 + m] = acc1[r];
        prow[2 * 16 + m] = acc2[r];
        prow[3 * 16 + m] = acc3[r];
    }
    // diagonal tiles: element (row==col) lives in tile nt==w at lanes m>>2==q
    if (ti == tj && (m >> 2) == q) {
        const f32x4 accw = (w == 0) ? acc0 : (w == 1) ? acc1 : (w == 2) ? acc2 : acc3;
        ndiag[ks * BSZ + i0 + w * 16 + m] = accw[m & 3];
    }
}

// ---------------------------------------------------------------------------
// Kernel 2: per-anchor triplet sum, self-contained finalize (R10/R11
// proven form).  nrm staged in LDS from 4 ndiag partials, distance on the
// fly from 4 partial streams, ballot compaction, |P|x|N| scan.  Each block
// computes V redundantly from a local LDS type-histogram and adds
// (blocksum/V) to out[0] with ONE plain device atomicAdd — no
// acquire/release, no ticket.  Block 0 adds the closed-form invalid-triplet
// term (B^3-V)*margin/V (reference adds margin to ALL entries pre-clamp,
// so each invalid triplet contributes exactly margin).
// ---------------------------------------------------------------------------
__global__ __launch_bounds__(256) void triplet_kernel(
    const float* __restrict__ part, const float* __restrict__ ndiag,
    const int* __restrict__ types, float* __restrict__ out)
{
    const int a = blockIdx.x;
    const int tid = threadIdx.x;
    const int lane = tid & 63;
    __shared__ float nrm[BSZ];
    __shared__ float pos[BSZ], neg[BSZ];
    __shared__ int npos, nneg;
    __shared__ float wsum[4];
    __shared__ int cnt[NTYPES];
    if (tid == 0) { npos = 0; nneg = 0; }
    if (tid < NTYPES) cnt[tid] = 0;
    for (int j = tid; j < BSZ; j += 256)
        nrm[j] = ndiag[j] + ndiag[BSZ + j] + ndiag[2 * BSZ + j] + ndiag[3 * BSZ + j];
    const int ta = types[a];
    __syncthreads();

    const float na = nrm[a];
    const size_t rb = (size_t)a * BSZ;
    const size_t PS = (size_t)BSZ * BSZ;

    for (int j = tid; j < BSZ; j += 256) {
        const int tj = types[j];
        atomicAdd(&cnt[tj], 1);                      // local histogram for V
        const float sp = part[rb + j] + part[PS + rb + j]
                       + part[2 * PS + rb + j] + part[3 * PS + rb + j];
        const float d = sqrtf(fmaxf(na + nrm[j] - 2.f * sp, 0.f));
        const bool isp = (tj == ta);
        const unsigned long long mm = __ballot(isp);
        const unsigned long long below = mm & ((1ull << lane) - 1ull);
        const int cp = __popcll(mm);
        int basep = 0, basen = 0;
        if (lane == 0) {
            basep = atomicAdd(&npos, cp);
            basen = atomicAdd(&nneg, 64 - cp);
        }
        basep = __shfl(basep, 0);
        basen = __shfl(basen, 0);
        const int pbelow = (int)__popcll(below);
        if (isp) pos[basep + pbelow] = d;
        else     neg[basen + (lane - pbelow)] = d;
    }
    __syncthreads();
    const int np = npos, nn = nneg;

    float local = 0.f;
    for (int pi = 0; pi < np; ++pi) {
        const float dpm = pos[pi] + MARGIN;          // broadcast LDS read
        for (int n = tid; n < nn; n += 256)
            local += fmaxf(dpm - neg[n], 0.f);
    }

    #pragma unroll
    for (int off = 32; off > 0; off >>= 1) local += __shfl_down(local, off);
    if (lane == 0) wsum[tid >> 6] = local;
    __syncthreads();
    if (tid == 0) {
        long long V = 0;
        #pragma unroll
        for (int t = 0; t < NTYPES; ++t) {
            long long c = cnt[t];
            V += c * c * (long long)(BSZ - c);
        }
        double blocksum = (double)wsum[0] + (double)wsum[1]
                        + (double)wsum[2] + (double)wsum[3];
        float contrib = (float)(blocksum / (double)V);
        if (a == 0) {
            const long long B3 = (long long)BSZ * BSZ * BSZ;
            contrib += (float)((double)(B3 - V) * (double)MARGIN / (double)V);
        }
        atomicAdd(out, contrib);                     // plain relaxed atomic
    }
}

extern "C" void kernel_launch(void* const* d_in, const int* in_sizes, int n_in,
                              void* d_out, int out_size, void* d_ws, size_t ws_size,
                              hipStream_t stream) {
    const int* types = (const int*)d_in[0];
    const float* emb = (const float*)d_in[1];
    float* out = (float*)d_out;

    float* part = (float*)d_ws;                               // 4 MB
    float* ndiag = part + (size_t)KSPLIT * BSZ * BSZ;         // 8 KB

    dot_partial_kernel<<<256, 256, 0, stream>>>(emb, part, ndiag, out);
    triplet_kernel<<<BSZ, 256, 0, stream>>>(part, ndiag, types, out);
}